// Round 8
// baseline (211.591 us; speedup 1.0000x reference)
//
#include <hip/hip_runtime.h>
#include <hip/hip_bf16.h>

typedef __attribute__((ext_vector_type(8))) short short8;   // 8 bf16 (4 VGPRs)
typedef __attribute__((ext_vector_type(4))) float floatx4;  // MFMA C/D

// (B,T,D) = (128,1024,64) fp32. out[i][j][t] = prod_{s<=t}(1 + <dX(s-1),dY(s-1)>/dt)
constexpr int BX    = 128;
constexpr int TT    = 1024;
constexpr int DDIM  = 64;
constexpr int NPAIR = BX * BX;
constexpr int FCH   = 16;              // fine chunk (pass1 / scan granularity)
constexpr int NFCH  = TT / FCH;        // 64
constexpr float DT_INV = 1023.0f;

// LDS element index for bf16 rows of 64 with XOR-segment swizzle (16B segments).
__device__ __forceinline__ int sidxE(int row, int k) {
    return row * 64 + ((((k >> 3) ^ (row & 7)) << 3) | (k & 7));
}

__device__ __forceinline__ ushort f2bf(float f) {           // round-to-nearest-even bf16
    uint u = __builtin_bit_cast(uint, f);
    u += 0x7fffu + ((u >> 16) & 1u);
    return (ushort)(u >> 16);
}

// 8 floats -> hi/lo bf16 split via packed bf16 converts, two 16B LDS stores.
__device__ __forceinline__ void cvt_store(ushort* hiP, ushort* loP, const float* v) {
    uint hw[4], lw[4];
#pragma unroll
    for (int p = 0; p < 4; ++p) {
        const __hip_bfloat162 h = __float22bfloat162_rn(make_float2(v[2 * p], v[2 * p + 1]));
        const float r0 = v[2 * p]     - __bfloat162float(h.x);
        const float r1 = v[2 * p + 1] - __bfloat162float(h.y);
        const __hip_bfloat162 l = __float22bfloat162_rn(make_float2(r0, r1));
        hw[p] = (uint)__bfloat16_as_ushort(h.x) | ((uint)__bfloat16_as_ushort(h.y) << 16);
        lw[p] = (uint)__bfloat16_as_ushort(l.x) | ((uint)__bfloat16_as_ushort(l.y) << 16);
    }
    *(uint4*)hiP = make_uint4(hw[0], hw[1], hw[2], hw[3]);
    *(uint4*)loP = make_uint4(lw[0], lw[1], lw[2], lw[3]);
}

__device__ __forceinline__ void ld8(const float* p, float* dst) {
    const float4 a = *(const float4*)p;
    const float4 b = *(const float4*)(p + 4);
    dst[0] = a.x; dst[1] = a.y; dst[2] = a.z; dst[3] = a.w;
    dst[4] = b.x; dst[5] = b.y; dst[6] = b.z; dst[7] = b.w;
}

// Recompute 2-pass scheme. 32i x 32j tiles, wave w owns (w>>1,w&1) 16x16 subtile.
// PASS 1: STEPS=16, 1024 blocks (4/CU): chunk totals -> P[fine_chunk][pair]. ~2MB writes.
// PASS 2: STEPS=32, 512 blocks (2/CU): cum starts at exclusive prefix (from scan),
//         recomputes the steps, writes FINAL values to out as full-128B line runs.
// XCD grouping: linearID%8 == cz%8 -> all tiles of a chunk share one XCD's L2.
template<int PASS>
__global__ __launch_bounds__(256, (PASS == 1) ? 4 : 2)
void zpass_kernel(const float* __restrict__ X, const float* __restrict__ Y,
                  float* __restrict__ out, float* __restrict__ P)
{
    constexpr int STEPS = (PASS == 1) ? 16 : 32;

    __shared__ __align__(16) ushort smXhi[2][32 * 64], smXlo[2][32 * 64];  // 16 KB
    __shared__ __align__(16) ushort smYhi[2][32 * 64], smYlo[2][32 * 64];  // 16 KB

    // swizzled decode: L = (cz&7) + 8*(tile + 16*(cz>>3))
    const int L    = (int)blockIdx.x;
    const int tile = (L >> 3) & 15;              // 0..15
    const int cz   = ((L >> 7) << 3) | (L & 7);  // pass1: 0..63, pass2: 0..31
    const int i0 = (tile & 3) * 32;
    const int j0 = (tile >> 2) * 32;
    const int t0 = cz * STEPS;
    const int tid  = (int)threadIdx.x;
    const int lane = tid & 63, w = tid >> 6, quad = lane >> 4, l15 = lane & 15;
    const int wr = w >> 1, wc = w & 1;
    const int pbase = (i0 + wr * 16 + quad * 4) * BX + (j0 + wc * 16 + l15);

    float cum[4];
    if (PASS == 2) {                    // exclusive prefix at fine chunk 2*cz
#pragma unroll
        for (int r = 0; r < 4; ++r)
            cum[r] = P[(size_t)(cz * 2) * NPAIR + pbase + r * BX];
    } else {
#pragma unroll
        for (int r = 0; r < 4; ++r) cum[r] = 1.f;
    }

    const int srow = tid >> 3;          // 0..31
    const int sseg = tid & 7;
    const float* xp = X + (size_t)(i0 + srow) * TT * DDIM + sseg * 8;
    const float* yp = Y + (size_t)(j0 + srow) * TT * DDIM + sseg * 8;

    float cx[8], cy[8];                 // slice t0+h values
    float rx[2][8], ry[2][8];           // 2-deep prefetch ring
    {
        const int sa = (t0 == 0) ? 0 : (t0 - 1);
        float pvx[8], pvy[8], d[8];
        ld8(xp + (size_t)t0 * DDIM, cx);
        ld8(yp + (size_t)t0 * DDIM, cy);
        ld8(xp + (size_t)sa * DDIM, pvx);
        ld8(yp + (size_t)sa * DDIM, pvy);
        ld8(xp + (size_t)(t0 + 1) * DDIM, rx[1]);   // slice t0+1 -> set 1
        ld8(yp + (size_t)(t0 + 1) * DDIM, ry[1]);

#pragma unroll
        for (int k = 0; k < 8; ++k) d[k] = cx[k] - pvx[k];
        cvt_store(&smXhi[0][sidxE(srow, sseg * 8)], &smXlo[0][sidxE(srow, sseg * 8)], d);
#pragma unroll
        for (int k = 0; k < 8; ++k) d[k] = cy[k] - pvy[k];
        cvt_store(&smYhi[0][sidxE(srow, sseg * 8)], &smYlo[0][sidxE(srow, sseg * 8)], d);
    }

    uint histP[4][STEPS / 2];           // bf16-packed history (PASS2 only; dead in PASS1)

    __syncthreads();

#pragma unroll
    for (int h = 0; h < STEPS; ++h) {
        const int cur = h & 1;

        if (h + 2 < STEPS) {            // prefetch slice t0+h+2 into ring set h&1
            const size_t u = (size_t)(t0 + h + 2) * DDIM;
            ld8(xp + u, rx[h & 1]); ld8(yp + u, ry[h & 1]);
        }

        short8 aHi[2], aLo[2];
#pragma unroll
        for (int kk = 0; kk < 2; ++kk) {
            const int e = sidxE(wr * 16 + l15, kk * 32 + quad * 8);
            aHi[kk] = *(const short8*)&smXhi[cur][e];
            aLo[kk] = *(const short8*)&smXlo[cur][e];
        }

        floatx4 acc = {0.f, 0.f, 0.f, 0.f};
#pragma unroll
        for (int kk = 0; kk < 2; ++kk) {
            const int e = sidxE(wc * 16 + l15, kk * 32 + quad * 8);
            const short8 bHi = *(const short8*)&smYhi[cur][e];
            const short8 bLo = *(const short8*)&smYlo[cur][e];
            acc = __builtin_amdgcn_mfma_f32_16x16x32_bf16(aLo[kk], bHi, acc, 0, 0, 0);
            acc = __builtin_amdgcn_mfma_f32_16x16x32_bf16(aHi[kk], bLo, acc, 0, 0, 0);
            acc = __builtin_amdgcn_mfma_f32_16x16x32_bf16(aHi[kk], bHi, acc, 0, 0, 0);
        }
#pragma unroll
        for (int r = 0; r < 4; ++r) {
            cum[r] *= fmaf(acc[r], DT_INV, 1.f);
            if (PASS == 2) {            // pack scaled value (prefix already folded in)
                const uint hb = (uint)f2bf(cum[r]);
                if ((h & 1) == 0) histP[r][h >> 1] = hb;
                else              histP[r][h >> 1] |= (hb << 16);
            }
        }

        if (h + 1 < STEPS) {            // stage next step's diffs into other buffer
            const int nsel = (h + 1) & 1;
            float d[8];
#pragma unroll
            for (int k = 0; k < 8; ++k) d[k] = rx[nsel][k] - cx[k];
            cvt_store(&smXhi[cur ^ 1][sidxE(srow, sseg * 8)], &smXlo[cur ^ 1][sidxE(srow, sseg * 8)], d);
#pragma unroll
            for (int k = 0; k < 8; ++k) d[k] = ry[nsel][k] - cy[k];
            cvt_store(&smYhi[cur ^ 1][sidxE(srow, sseg * 8)], &smYlo[cur ^ 1][sidxE(srow, sseg * 8)], d);
#pragma unroll
            for (int k = 0; k < 8; ++k) { cx[k] = rx[nsel][k]; cy[k] = ry[nsel][k]; }
            __syncthreads();
        }
    }

    if (PASS == 1) {                    // fp32 fine-chunk totals
#pragma unroll
        for (int r = 0; r < 4; ++r)
            P[(size_t)cz * NPAIR + pbase + r * BX] = cum[r];
    } else {                            // final scaled values: full 128B line per pair
#pragma unroll
        for (int r = 0; r < 4; ++r) {
            float* o = out + (size_t)(pbase + r * BX) * TT + t0;
#pragma unroll
            for (int q = 0; q < STEPS / 4; ++q) {
                const uint u0 = histP[r][2 * q];
                const uint u1 = histP[r][2 * q + 1];
                *(float4*)(o + q * 4) = make_float4(
                    __builtin_bit_cast(float, u0 << 16),
                    __builtin_bit_cast(float, u0 & 0xffff0000u),
                    __builtin_bit_cast(float, u1 << 16),
                    __builtin_bit_cast(float, u1 & 0xffff0000u));
            }
        }
    }
}

// Exclusive prefix product over the 64 fine chunks, in place. 256 blocks x 64 thr
// (one wave per CU); loads all 64 values (independent, coalesced), then stores.
__global__ __launch_bounds__(64) void scan_kernel(float* __restrict__ P)
{
    const int p = (int)blockIdx.x * 64 + (int)threadIdx.x;
    float v[NFCH];
#pragma unroll
    for (int c = 0; c < NFCH; ++c) v[c] = P[(size_t)c * NPAIR + p];
    float run = 1.f;
#pragma unroll
    for (int c = 0; c < NFCH; ++c) {
        const float t = v[c];
        P[(size_t)c * NPAIR + p] = run;
        run *= t;
    }
}

extern "C" void kernel_launch(void* const* d_in, const int* in_sizes, int n_in,
                              void* d_out, int out_size, void* d_ws, size_t ws_size,
                              hipStream_t stream)
{
    const float* X = (const float*)d_in[0];
    const float* Y = (const float*)d_in[1];
    float* out = (float*)d_out;
    float* P   = (float*)d_ws;          // NFCH*NPAIR*4 = 4 MB

    zpass_kernel<1><<<dim3(1024), 256, 0, stream>>>(X, Y, out, P);
    scan_kernel<<<dim3(NPAIR / 64), 64, 0, stream>>>(P);
    zpass_kernel<2><<<dim3(512), 256, 0, stream>>>(X, Y, out, P);
}

// Round 9
// 149.031 us; speedup vs baseline: 1.4198x; 1.4198x over previous
//
#include <hip/hip_runtime.h>
#include <hip/hip_bf16.h>

typedef __attribute__((ext_vector_type(8))) short short8;   // 8 bf16 (4 VGPRs)
typedef __attribute__((ext_vector_type(4))) float floatx4;  // MFMA C/D

// (B,T,D) = (128,1024,64) fp32. out[i][j][t] = prod_{s<=t}(1 + <dX(s-1),dY(s-1)>/dt)
constexpr int BX    = 128;
constexpr int TT    = 1024;
constexpr int DDIM  = 64;
constexpr int NPAIR = BX * BX;
constexpr int LCH   = 16;              // t-steps per block
constexpr int NCH   = TT / LCH;        // 64
constexpr float DT_INV = 1023.0f;

// LDS element index for bf16 rows of 64 with XOR-segment swizzle (16B segments).
__device__ __forceinline__ int sidxE(int row, int k) {
    return row * 64 + ((((k >> 3) ^ (row & 7)) << 3) | (k & 7));
}

__device__ __forceinline__ ushort f2bf(float f) {           // round-to-nearest-even bf16
    uint u = __builtin_bit_cast(uint, f);
    u += 0x7fffu + ((u >> 16) & 1u);
    return (ushort)(u >> 16);
}

// 8 floats -> hi/lo bf16 split via packed bf16 converts, two 16B LDS stores.
__device__ __forceinline__ void cvt_store(ushort* hiP, ushort* loP, const float* v) {
    uint hw[4], lw[4];
#pragma unroll
    for (int p = 0; p < 4; ++p) {
        const __hip_bfloat162 h = __float22bfloat162_rn(make_float2(v[2 * p], v[2 * p + 1]));
        const float r0 = v[2 * p]     - __bfloat162float(h.x);
        const float r1 = v[2 * p + 1] - __bfloat162float(h.y);
        const __hip_bfloat162 l = __float22bfloat162_rn(make_float2(r0, r1));
        hw[p] = (uint)__bfloat16_as_ushort(h.x) | ((uint)__bfloat16_as_ushort(h.y) << 16);
        lw[p] = (uint)__bfloat16_as_ushort(l.x) | ((uint)__bfloat16_as_ushort(l.y) << 16);
    }
    *(uint4*)hiP = make_uint4(hw[0], hw[1], hw[2], hw[3]);
    *(uint4*)loP = make_uint4(lw[0], lw[1], lw[2], lw[3]);
}

__device__ __forceinline__ void ld8(const float* p, float* dst) {
    const float4 a = *(const float4*)p;
    const float4 b = *(const float4*)(p + 4);
    dst[0] = a.x; dst[1] = a.y; dst[2] = a.z; dst[3] = a.w;
    dst[4] = b.x; dst[5] = b.y; dst[6] = b.z; dst[7] = b.w;
}

// Kernel A: 64i x 32j pair tile x 16 t-steps. Split-bf16 3-term MFMA dots.
// 512 blocks XCD-grouped (linearID%8 == cz%8), 2/CU. 4-deep global prefetch ring
// (~3 steps of cover vs ~900cy HBM latency; the per-step barrier waits on
// straggler loads, which round 7 showed occupancy alone cannot hide).
// WP=1: bf16-PACKED history -> W[cz][pair] (32B/pair, 16-lane 512B spans, no
//       write amplification). WP=0: legacy direct f32 [pair][t] stores.
template<int WP>
__global__ __launch_bounds__(256, 2) void zchunk_kernel(const float* __restrict__ X,
                                                        const float* __restrict__ Y,
                                                        float* __restrict__ dstF,
                                                        uint*  __restrict__ Wp,
                                                        float* __restrict__ P)
{
    __shared__ __align__(16) ushort smXhi[2][64 * 64], smXlo[2][64 * 64];  // 32 KB
    __shared__ __align__(16) ushort smYhi[2][32 * 64], smYlo[2][32 * 64];  // 16 KB

    // swizzled decode: L = (cz&7) + 8*(tile + 8*(cz>>3))
    const int L    = (int)blockIdx.x;          // 0..511
    const int tile = (L >> 3) & 7;             // 0..7
    const int cz   = ((L >> 6) << 3) | (L & 7);// 0..63
    const int i0 = (tile & 1) * 64;
    const int j0 = (tile >> 1) * 32;
    const int t0 = cz * LCH;
    const int tid  = (int)threadIdx.x;
    const int lane = tid & 63, w = tid >> 6, quad = lane >> 4, l15 = lane & 15;

    const int srow = tid >> 3;          // 0..31
    const int sseg = tid & 7;
    const float* xp0 = X + (size_t)(i0 + srow)      * TT * DDIM + sseg * 8;
    const float* xp1 = X + (size_t)(i0 + srow + 32) * TT * DDIM + sseg * 8;
    const float* yp  = Y + (size_t)(j0 + srow)      * TT * DDIM + sseg * 8;

    float cx0[8], cx1[8], cy[8];              // slice t0+h values
    float rx0[4][8], rx1[4][8], ry[4][8];     // 4-deep prefetch ring (slot = t&3)
    {
        const int sa = (t0 == 0) ? 0 : (t0 - 1);
        float pv0[8], pv1[8], pv2[8], d[8];
        ld8(xp0 + (size_t)t0 * DDIM, cx0);
        ld8(xp1 + (size_t)t0 * DDIM, cx1);
        ld8(yp  + (size_t)t0 * DDIM, cy);
        ld8(xp0 + (size_t)sa * DDIM, pv0);
        ld8(xp1 + (size_t)sa * DDIM, pv1);
        ld8(yp  + (size_t)sa * DDIM, pv2);
#pragma unroll
        for (int s = 1; s <= 3; ++s) {        // slices t0+1..t0+3 -> slots 1..3
            ld8(xp0 + (size_t)(t0 + s) * DDIM, rx0[s]);
            ld8(xp1 + (size_t)(t0 + s) * DDIM, rx1[s]);
            ld8(yp  + (size_t)(t0 + s) * DDIM, ry[s]);
        }

#pragma unroll
        for (int k = 0; k < 8; ++k) d[k] = cx0[k] - pv0[k];
        cvt_store(&smXhi[0][sidxE(srow, sseg * 8)], &smXlo[0][sidxE(srow, sseg * 8)], d);
#pragma unroll
        for (int k = 0; k < 8; ++k) d[k] = cx1[k] - pv1[k];
        cvt_store(&smXhi[0][sidxE(srow + 32, sseg * 8)], &smXlo[0][sidxE(srow + 32, sseg * 8)], d);
#pragma unroll
        for (int k = 0; k < 8; ++k) d[k] = cy[k] - pv2[k];
        cvt_store(&smYhi[0][sidxE(srow, sseg * 8)], &smYlo[0][sidxE(srow, sseg * 8)], d);
    }

    float cum[2][4];
    uint  histP[2][4][8];               // bf16-packed 16-step history (static-indexed)
#pragma unroll
    for (int s = 0; s < 2; ++s)
#pragma unroll
        for (int r = 0; r < 4; ++r) cum[s][r] = 1.f;

    __syncthreads();

#pragma unroll
    for (int h = 0; h < LCH; ++h) {
        const int cur = h & 1;

        if (h + 4 < LCH) {              // prefetch slice t0+h+4 into slot (h+4)&3 = h&3
            const size_t u = (size_t)(t0 + h + 4) * DDIM;
            ld8(xp0 + u, rx0[h & 3]); ld8(xp1 + u, rx1[h & 3]); ld8(yp + u, ry[h & 3]);
        }

        short8 aHi[2], aLo[2];
#pragma unroll
        for (int kk = 0; kk < 2; ++kk) {
            const int e = sidxE(w * 16 + l15, kk * 32 + quad * 8);
            aHi[kk] = *(const short8*)&smXhi[cur][e];
            aLo[kk] = *(const short8*)&smXlo[cur][e];
        }

#pragma unroll
        for (int sub = 0; sub < 2; ++sub) {
            floatx4 acc = {0.f, 0.f, 0.f, 0.f};
#pragma unroll
            for (int kk = 0; kk < 2; ++kk) {
                const int e = sidxE(sub * 16 + l15, kk * 32 + quad * 8);
                const short8 bHi = *(const short8*)&smYhi[cur][e];
                const short8 bLo = *(const short8*)&smYlo[cur][e];
                acc = __builtin_amdgcn_mfma_f32_16x16x32_bf16(aLo[kk], bHi, acc, 0, 0, 0);
                acc = __builtin_amdgcn_mfma_f32_16x16x32_bf16(aHi[kk], bLo, acc, 0, 0, 0);
                acc = __builtin_amdgcn_mfma_f32_16x16x32_bf16(aHi[kk], bHi, acc, 0, 0, 0);
            }
#pragma unroll
            for (int r = 0; r < 4; ++r) {
                cum[sub][r] *= fmaf(acc[r], DT_INV, 1.f);
                const uint hb = (uint)f2bf(cum[sub][r]);
                if ((h & 1) == 0) histP[sub][r][h >> 1] = hb;
                else              histP[sub][r][h >> 1] |= (hb << 16);
            }
        }

        if (h + 1 < LCH) {              // stage next step's diffs (ring slot (h+1)&3)
            const int nsel = (h + 1) & 3;
            float d[8];
#pragma unroll
            for (int k = 0; k < 8; ++k) d[k] = rx0[nsel][k] - cx0[k];
            cvt_store(&smXhi[cur ^ 1][sidxE(srow, sseg * 8)], &smXlo[cur ^ 1][sidxE(srow, sseg * 8)], d);
#pragma unroll
            for (int k = 0; k < 8; ++k) d[k] = rx1[nsel][k] - cx1[k];
            cvt_store(&smXhi[cur ^ 1][sidxE(srow + 32, sseg * 8)], &smXlo[cur ^ 1][sidxE(srow + 32, sseg * 8)], d);
#pragma unroll
            for (int k = 0; k < 8; ++k) d[k] = ry[nsel][k] - cy[k];
            cvt_store(&smYhi[cur ^ 1][sidxE(srow, sseg * 8)], &smYlo[cur ^ 1][sidxE(srow, sseg * 8)], d);
#pragma unroll
            for (int k = 0; k < 8; ++k) { cx0[k] = rx0[nsel][k]; cx1[k] = rx1[nsel][k]; cy[k] = ry[nsel][k]; }
            __syncthreads();
        }
    }

    // Epilogue: fp32 chunk totals + bf16-PACKED history (32B/pair -> W).
#pragma unroll
    for (int sub = 0; sub < 2; ++sub)
#pragma unroll
        for (int r = 0; r < 4; ++r) {
            const int pair = (i0 + w * 16 + quad * 4 + r) * BX + (j0 + sub * 16 + l15);
            P[(size_t)cz * NPAIR + pair] = cum[sub][r];
            if (WP) {
                uint* o = Wp + ((size_t)cz * NPAIR + pair) * 8;   // 8 uints = 32B
                *(uint4*)o       = make_uint4(histP[sub][r][0], histP[sub][r][1],
                                              histP[sub][r][2], histP[sub][r][3]);
                *(uint4*)(o + 4) = make_uint4(histP[sub][r][4], histP[sub][r][5],
                                              histP[sub][r][6], histP[sub][r][7]);
            } else {
                float* o = dstF + (size_t)pair * TT + t0;
#pragma unroll
                for (int q = 0; q < 4; ++q) {
                    const uint u0 = histP[sub][r][2 * q];
                    const uint u1 = histP[sub][r][2 * q + 1];
                    *(float4*)(o + q * 4) = make_float4(
                        __builtin_bit_cast(float, u0 << 16),
                        __builtin_bit_cast(float, u0 & 0xffff0000u),
                        __builtin_bit_cast(float, u1 << 16),
                        __builtin_bit_cast(float, u1 & 0xffff0000u));
                }
            }
        }
}

// Kernel B (bf16-W): block = 16 pairs, 1024 blocks.
// Phase 1: parallel exclusive chunk-prefix -> pf[64][pair] (R5-proven).
// Phase 2a: waves load W tile (512B-contiguous per instruction) -> LDS (32KB).
// Phase 2b: per pair row, 256 threads unpack+scale; each wave stores 1KB
//           contiguous out (lines complete within one instruction).
__global__ __launch_bounds__(256) void scanscale_w(float* __restrict__ out,
                                                   const uint* __restrict__ W,
                                                   const float* __restrict__ P)
{
    __shared__ uint2 tileW[NCH * 65];   // [c][pr*4+tb] padded: 33.3 KB
    __shared__ float pf[NCH][17];       // [chunk][pair] padded
    __shared__ float tot[16][17];       // [seg][pair]

    const int p0  = (int)blockIdx.x * 16;
    const int tid = (int)threadIdx.x;
    const int p   = tid & 15;           // pair 0..15
    const int seg = tid >> 4;           // 0..15 (chunks seg*4..+3)

    float v[4], e[4];
#pragma unroll
    for (int k = 0; k < 4; ++k)
        v[k] = P[(size_t)(seg * 4 + k) * NPAIR + p0 + p];
    e[0] = 1.f;
#pragma unroll
    for (int k = 1; k < 4; ++k) e[k] = e[k - 1] * v[k - 1];
    tot[seg][p] = e[3] * v[3];
    __syncthreads();

    float base = 1.f;
#pragma unroll
    for (int q = 0; q < 15; ++q)
        if (q < seg) base *= tot[q][p];
#pragma unroll
    for (int k = 0; k < 4; ++k)
        pf[seg * 4 + k][p] = base * e[k];

    // Phase 2a: W -> LDS. Wave wv: chunks wv*16..+15; lane: pr=l>>2, tb=l&3.
    const int wv = tid >> 6, l = tid & 63;
    const int pr = l >> 2, tb = l & 3;
#pragma unroll
    for (int k = 0; k < 16; ++k) {
        const int c = wv * 16 + k;
        tileW[c * 65 + pr * 4 + tb] =
            *(const uint2*)(W + ((size_t)c * NPAIR + p0 + pr) * 8 + tb * 2);
    }
    __syncthreads();

    // Phase 2b: 16 rows; thread tid -> t=tid*4, c=tid>>2, q=tid&3.
    const int c2 = tid >> 2, q2 = tid & 3;
#pragma unroll 2
    for (int r = 0; r < 16; ++r) {
        const uint2 u = tileW[c2 * 65 + r * 4 + q2];
        const float f = pf[c2][r];
        *(float4*)(out + (size_t)(p0 + r) * TT + tid * 4) = make_float4(
            __builtin_bit_cast(float, u.x << 16) * f,
            __builtin_bit_cast(float, u.x & 0xffff0000u) * f,
            __builtin_bit_cast(float, u.y << 16) * f,
            __builtin_bit_cast(float, u.y & 0xffff0000u) * f);
    }
}

// Legacy fallback kernel B: scan+RMW-scale of out in place.
__global__ __launch_bounds__(256) void scanscale_kernel(float* __restrict__ out,
                                                        const float* __restrict__ P)
{
    __shared__ float pf[16][NCH];       // 4 KB
    const int p0  = (int)blockIdx.x * 16;
    const int tid = (int)threadIdx.x;

    if (tid < 16) {
        const int p = p0 + tid;
        float run = 1.f;
#pragma unroll 4
        for (int c = 0; c < NCH; ++c) {
            pf[tid][c] = run;
            run *= P[(size_t)c * NPAIR + p];
        }
    }
    __syncthreads();

    const int pp  = tid >> 4;
    const int col = tid & 15;
    float* row = out + (size_t)(p0 + pp) * TT;
#pragma unroll
    for (int seg = 0; seg < 16; ++seg) {
        const int t = seg * 64 + col * 4;
        const float f = pf[pp][t >> 4];
        float4 v = *(float4*)(row + t);
        v.x *= f; v.y *= f; v.z *= f; v.w *= f;
        *(float4*)(row + t) = v;
    }
}

extern "C" void kernel_launch(void* const* d_in, const int* in_sizes, int n_in,
                              void* d_out, int out_size, void* d_ws, size_t ws_size,
                              hipStream_t stream)
{
    const float* X = (const float*)d_in[0];
    const float* Y = (const float*)d_in[1];
    float* out = (float*)d_out;
    float* P   = (float*)d_ws;                          // 4 MB
    uint*  W   = (uint*)((float*)d_ws + (size_t)NCH * NPAIR);  // 32 MB bf16-packed

    const size_t need = (size_t)NCH * NPAIR * (4 + 32); // P + W
    if (ws_size >= need) {
        zchunk_kernel<1><<<dim3(512), 256, 0, stream>>>(X, Y, out, W, P);
        scanscale_w<<<dim3(NPAIR / 16), 256, 0, stream>>>(out, W, P);
    } else {
        zchunk_kernel<0><<<dim3(512), 256, 0, stream>>>(X, Y, out, W, P);
        scanscale_kernel<<<dim3(NPAIR / 16), 256, 0, stream>>>(out, P);
    }
}